// Round 9
// baseline (496.177 us; speedup 1.0000x reference)
//
#include <hip/hip_runtime.h>
#include <hip/hip_bf16.h>

#define NB 2
#define SEQ 2048
#define DMODEL 2048
#define NH 16
#define HD 128
// SM_SCALE * log2(e): softmax computed in exp2 domain
#define QSCALE (0.08838834764831845f * 1.44269504088896f)
#define THRL2 11.5f

using bf16x8 = __attribute__((ext_vector_type(8))) __bf16;
using f32x4  = __attribute__((ext_vector_type(4))) float;

#define MFMA16 __builtin_amdgcn_mfma_f32_16x16x32_bf16

typedef __attribute__((address_space(1))) const void* gptr_t;
typedef __attribute__((address_space(3))) void* lptr_t;

__device__ inline void gload_lds16(const unsigned short* g, unsigned short* l) {
    __builtin_amdgcn_global_load_lds((gptr_t)g, (lptr_t)l, 16, 0, 0);
}

__device__ inline unsigned short f2b(float f) {
    unsigned u = __builtin_bit_cast(unsigned, f);
    u += 0x7FFF + ((u >> 16) & 1);
    return (unsigned short)(u >> 16);
}
__device__ inline float b2f(unsigned short h) {
    return __builtin_bit_cast(float, (unsigned)h << 16);
}
__device__ inline float fexp2(float x) {
    float r;
    asm("v_exp_f32 %0, %1" : "=v"(r) : "v"(x));
    return r;
}
__device__ inline unsigned cvtpk(float a, float b) {   // low=bf16(a), high=bf16(b)
    unsigned r;
    asm("v_cvt_pk_bf16_f32 %0, %1, %2" : "=v"(r) : "v"(a), "v"(b));
    return r;
}

// ---------------- cast fp32 -> bf16, 4 elems/thread ----------------
__global__ void cast_f2b(const float* __restrict__ src, unsigned short* __restrict__ dst, int n) {
    int i = (blockIdx.x * 256 + threadIdx.x) * 4;
    if (i + 3 < n) {
        float4 v = *reinterpret_cast<const float4*>(src + i);
        ushort4 o;
        o.x = f2b(v.x); o.y = f2b(v.y); o.z = f2b(v.z); o.w = f2b(v.w);
        *reinterpret_cast<ushort4*>(dst + i) = o;
    }
}

// ---------------- GEMM (m97 structure, unchanged) ----------------
template<int OUT_BF16>
__global__ __launch_bounds__(256) void gemm_lds(const unsigned short* __restrict__ A,
                                                const unsigned short* __restrict__ Bw,
                                                void* __restrict__ Cout,
                                                int M, int N, int K) {
    __shared__ __align__(16) unsigned short As[128 * 32];
    __shared__ __align__(16) unsigned short Bs[128 * 32];
    int tid = threadIdx.x;
    int lane = tid & 63;
    int w = tid >> 6;
    int row0 = blockIdx.y * 128;
    int col0 = blockIdx.x * 128;

    const unsigned short *pA[2], *pB[2];
    unsigned short *lA[2], *lB[2];
#pragma unroll
    for (int j = 0; j < 2; j++) {
        int c = j * 256 + w * 64 + lane;
        int row = c >> 2;
        int kc = c & 3;
        int ks = kc ^ ((row >> 1) & 3);
        pA[j] = A  + (size_t)(row0 + row) * K + ks * 8;
        pB[j] = Bw + (size_t)(col0 + row) * K + ks * 8;
        int basechunk = j * 256 + w * 64;
        lA[j] = As + basechunk * 8;
        lB[j] = Bs + basechunk * 8;
    }

    int wr = w >> 1, wc = w & 1;
    int lr = lane & 15, g = lane >> 4;
    int offA[4], offB[4];
#pragma unroll
    for (int i = 0; i < 4; i++) {
        int ra = wr * 64 + i * 16 + lr;
        offA[i] = ra * 32 + (g ^ ((ra >> 1) & 3)) * 8;
        int rb = wc * 64 + i * 16 + lr;
        offB[i] = rb * 32 + (g ^ ((rb >> 1) & 3)) * 8;
    }

    f32x4 acc[4][4] = {};

    for (int k = 0; k < K; k += 32) {
#pragma unroll
        for (int j = 0; j < 2; j++) {
            gload_lds16(pA[j] + k, lA[j]);
            gload_lds16(pB[j] + k, lB[j]);
        }
        __syncthreads();

        bf16x8 a[4], b[4];
#pragma unroll
        for (int i = 0; i < 4; i++) a[i] = *reinterpret_cast<const bf16x8*>(As + offA[i]);
#pragma unroll
        for (int j2 = 0; j2 < 4; j2++) b[j2] = *reinterpret_cast<const bf16x8*>(Bs + offB[j2]);
#pragma unroll
        for (int i = 0; i < 4; i++)
#pragma unroll
            for (int j2 = 0; j2 < 4; j2++)
                acc[i][j2] = MFMA16(a[i], b[j2], acc[i][j2], 0, 0, 0);
        __syncthreads();
    }

    int orow = g * 4;
#pragma unroll
    for (int i = 0; i < 4; i++) {
#pragma unroll
        for (int j = 0; j < 4; j++) {
            int r0 = row0 + wr * 64 + i * 16 + orow;
            int c  = col0 + wc * 64 + j * 16 + lr;
#pragma unroll
            for (int r = 0; r < 4; r++) {
                float v = acc[i][j][r];
                if (OUT_BF16)
                    ((unsigned short*)Cout)[(size_t)(r0 + r) * N + c] = f2b(v);
                else
                    ((float*)Cout)[(size_t)(r0 + r) * N + c] = v;
            }
        }
    }
}

// ---------------- RoPE + rearrange Q,K (Q pre-scaled by SM_SCALE*log2e) ----------------
__global__ void rope_qk(const unsigned short* __restrict__ qkv,
                        unsigned short* __restrict__ qb,
                        unsigned short* __restrict__ kb) {
    int idx = blockIdx.x * 256 + threadIdx.x;
    int i = idx & 63;
    int h = (idx >> 6) & 15;
    int t = idx >> 10;
    int s = t & (SEQ - 1);
    int b = t >> 11;

    float inv = exp2f(-13.287712379549449f * (float)i * (1.0f / 64.0f));
    float ang = (float)s * inv;
    float sn, cs;
    sincosf(ang, &sn, &cs);

    const unsigned short* base = qkv + (size_t)t * 6144 + h * 128 + 2 * i;
    unsigned qv = *reinterpret_cast<const unsigned*>(base);
    unsigned kv = *reinterpret_cast<const unsigned*>(base + 2048);

    float qe = b2f((unsigned short)(qv & 0xFFFF));
    float qo = b2f((unsigned short)(qv >> 16));
    float ke = b2f((unsigned short)(kv & 0xFFFF));
    float ko = b2f((unsigned short)(kv >> 16));

    float qe2 = (qe * cs - qo * sn) * QSCALE;
    float qo2 = (qe * sn + qo * cs) * QSCALE;
    float ke2 = ke * cs - ko * sn;
    float ko2 = ke * sn + ko * cs;

    size_t o = ((size_t)(b * NH + h) * SEQ + s) * HD + 2 * i;
    *reinterpret_cast<unsigned*>(qb + o) = (unsigned)f2b(qe2) | ((unsigned)f2b(qo2) << 16);
    *reinterpret_cast<unsigned*>(kb + o) = (unsigned)f2b(ke2) | ((unsigned)f2b(ko2) << 16);
}

// ---------------- V rearrange: qkv -> vt [B][H][HD][S] ----------------
__global__ void v_rearr(const unsigned short* __restrict__ qkv, unsigned short* __restrict__ vt) {
    int idx = blockIdx.x * 256 + threadIdx.x;
    int s4 = (idx & 511) * 4;
    int d  = (idx >> 9) & 127;
    int h  = (idx >> 16) & 15;
    int b  = idx >> 20;
    ushort4 o;
    size_t rbase = (size_t)(b * SEQ + s4) * 6144 + 4096 + h * 128 + d;
    o.x = qkv[rbase];
    o.y = qkv[rbase + 6144];
    o.z = qkv[rbase + 2 * 6144];
    o.w = qkv[rbase + 3 * 6144];
    *reinterpret_cast<ushort4*>(vt + ((size_t)(b * NH + h) * HD + d) * SEQ + s4) = o;
}

// ---------------- flash attention v5 ----------------
// 1 wave/block, 64 threads. Block (p,bh) processes 32-row q-tiles p and 63-p
// sequentially -> uniform 33 KV-trips/block. No barriers (single wave, in-order DS).
// K single-buffered in LDS (16KB, XOR-swizzled), reg-staged in 2 halves; P 4KB.
// 20KB LDS -> 8 blocks/CU = 2 waves/SIMD sustained.
__global__ __launch_bounds__(64, 2) void attn5(const unsigned short* __restrict__ Q,
                                               const unsigned short* __restrict__ Kb,
                                               const unsigned short* __restrict__ Vt,
                                               unsigned short* __restrict__ O) {
    __shared__ __align__(16) char lds[20480];   // 16KB K + 4KB P

    int lane = threadIdx.x;
    int bid = blockIdx.x;
    int p  = bid >> 5;          // 0..31 -> pair (p, 63-p)
    int bh = bid & 31;          // bid%8 == bh%8 -> same head on same XCD
    int lr = lane & 15;
    int g  = lane >> 4;
    int g4 = g * 4;
    int lk = g * 8;

    const unsigned short* Qp = Q  + (size_t)bh * SEQ * HD;
    const unsigned short* Kp = Kb + (size_t)bh * SEQ * HD;
    const unsigned short* Vp = Vt + (size_t)bh * HD * SEQ;
    char* pl = lds + 16384;
    int b = bh >> 4;
    int h = bh & 15;

    for (int ph = 0; ph < 2; ++ph) {
        int j  = ph ? (63 - p) : p;
        int q0 = j * 32;
        int ktiles = (j >> 1) + 1;

        bf16x8 qf[2][4];
#pragma unroll
        for (int f = 0; f < 2; f++)
#pragma unroll
            for (int kb = 0; kb < 4; kb++)
                qf[f][kb] = *reinterpret_cast<const bf16x8*>(Qp + (size_t)(q0 + f * 16 + lr) * HD + kb * 32 + lk);

        f32x4 oacc[2][8] = {};
        float m[2] = { -1e30f, -1e30f }, l[2] = { 0.0f, 0.0f };
        int qrow[2] = { q0 + lr, q0 + 16 + lr };

        // prologue: stage KV tile 0 (rows r = h2*32 + cl*4 + g, chunk lr)
#pragma unroll
        for (int h2 = 0; h2 < 2; ++h2) {
            bf16x8 kst[8];
#pragma unroll
            for (int cl = 0; cl < 8; ++cl) {
                int r = h2 * 32 + cl * 4 + g;
                kst[cl] = *reinterpret_cast<const bf16x8*>(Kp + (size_t)r * HD + lr * 8);
            }
#pragma unroll
            for (int cl = 0; cl < 8; ++cl) {
                int r = h2 * 32 + cl * 4 + g;
                int byte = r * 256 + ((lr * 16) ^ ((r & 7) << 4));
                *reinterpret_cast<bf16x8*>(lds + byte) = kst[cl];
            }
        }

        for (int t = 0; t < ktiles; ++t) {
            int kv0 = t * 64;
            bool havenext = (t + 1 < ktiles);

            // issue half-A loads of next tile (latency hides under QK)
            bf16x8 kA[8];
            if (havenext) {
#pragma unroll
                for (int cl = 0; cl < 8; ++cl) {
                    int r = cl * 4 + g;
                    kA[cl] = *reinterpret_cast<const bf16x8*>(Kp + (size_t)(kv0 + 64 + r) * HD + lr * 8);
                }
            }

            // ---- QK^T swapped: lane owns q = lane&15, 16 in-lane kv scores ----
            f32x4 s[2][4] = {};
#pragma unroll
            for (int kb = 0; kb < 4; kb++) {
#pragma unroll
                for (int jj = 0; jj < 4; jj++) {
                    int row = jj * 16 + lr;
                    int cin = ((kb * 4 + g) ^ (row & 7));
                    bf16x8 kf = *reinterpret_cast<const bf16x8*>(lds + row * 256 + cin * 16);
                    s[0][jj] = MFMA16(kf, qf[0][kb], s[0][jj], 0, 0, 0);
                    s[1][jj] = MFMA16(kf, qf[1][kb], s[1][jj], 0, 0, 0);
                }
            }

            // write half A (DS pipe is in-order per wave: lands after QK reads)
            if (havenext) {
#pragma unroll
                for (int cl = 0; cl < 8; ++cl) {
                    int r = cl * 4 + g;
                    int byte = r * 256 + ((lr * 16) ^ ((r & 7) << 4));
                    *reinterpret_cast<bf16x8*>(lds + byte) = kA[cl];
                }
            }

            // issue half-B loads of next tile
            bf16x8 kB[8];
            if (havenext) {
#pragma unroll
                for (int cl = 0; cl < 8; ++cl) {
                    int r = 32 + cl * 4 + g;
                    kB[cl] = *reinterpret_cast<const bf16x8*>(Kp + (size_t)(kv0 + 64 + r) * HD + lr * 8);
                }
            }

            // ---- V prefetch (issue early, consumed at PV) ----
            bf16x8 vf[8][2];
#pragma unroll
            for (int db = 0; db < 8; db++)
#pragma unroll
                for (int ks = 0; ks < 2; ks++)
                    vf[db][ks] = *reinterpret_cast<const bf16x8*>(Vp + (size_t)(db * 16 + lr) * SEQ + kv0 + ks * 32 + lk);

            // ---- in-lane online softmax (exp2 domain, defer-max) ----
#pragma unroll
            for (int f = 0; f < 2; f++) {
                int q = qrow[f];
                bool full = (kv0 + 63 <= q0 + f * 16);   // wave-uniform
                float mx = -1e30f;
                if (full) {
#pragma unroll
                    for (int jj = 0; jj < 4; jj++)
#pragma unroll
                        for (int r = 0; r < 4; r++)
                            mx = fmaxf(mx, s[f][jj][r]);
                } else {
#pragma unroll
                    for (int jj = 0; jj < 4; jj++)
#pragma unroll
                        for (int r = 0; r < 4; r++) {
                            int kv = kv0 + jj * 16 + g4 + r;
                            float v = (kv <= q) ? s[f][jj][r] : -1e30f;
                            s[f][jj][r] = v;
                            mx = fmaxf(mx, v);
                        }
                }
                mx = fmaxf(mx, __shfl_xor(mx, 16));
                mx = fmaxf(mx, __shfl_xor(mx, 32));

                if (!__all(mx <= m[f] + THRL2)) {
                    float mn = fmaxf(m[f], mx);
                    float sc = fexp2(m[f] - mn);
                    m[f] = mn;
                    l[f] *= sc;
#pragma unroll
                    for (int db = 0; db < 8; db++)
#pragma unroll
                        for (int r = 0; r < 4; r++)
                            oacc[f][db][r] *= sc;
                }

                int row = f * 16 + lr;
                int rb = row * 128;
                int sw = (row & 7) << 4;
                float rs = 0.0f;
#pragma unroll
                for (int jj = 0; jj < 4; jj++)
#pragma unroll
                    for (int hh = 0; hh < 2; hh++) {
                        float p0 = fexp2(s[f][jj][2 * hh]     - m[f]);
                        float p1 = fexp2(s[f][jj][2 * hh + 1] - m[f]);
                        rs += p0 + p1;
                        unsigned pk = cvtpk(p0, p1);
                        int colb = jj * 32 + g * 8 + 4 * hh;
                        *reinterpret_cast<unsigned*>(pl + rb + (colb ^ sw)) = pk;
                    }
                rs += __shfl_xor(rs, 16);
                rs += __shfl_xor(rs, 32);
                l[f] += rs;
            }

            // write half B
            if (havenext) {
#pragma unroll
                for (int cl = 0; cl < 8; ++cl) {
                    int r = 32 + cl * 4 + g;
                    int byte = r * 256 + ((lr * 16) ^ ((r & 7) << 4));
                    *reinterpret_cast<bf16x8*>(lds + byte) = kB[cl];
                }
            }

            // ---- P fragments + swapped PV ----
            bf16x8 pb[2][2];
#pragma unroll
            for (int f = 0; f < 2; f++)
#pragma unroll
                for (int ks = 0; ks < 2; ks++) {
                    int row = f * 16 + lr;
                    int off = row * 128 + ((ks * 64 + g * 16) ^ ((row & 7) << 4));
                    pb[f][ks] = *reinterpret_cast<const bf16x8*>(pl + off);
                }
#pragma unroll
            for (int db = 0; db < 8; db++)
#pragma unroll
                for (int ks = 0; ks < 2; ks++) {
                    oacc[0][db] = MFMA16(vf[db][ks], pb[0][ks], oacc[0][db], 0, 0, 0);
                    oacc[1][db] = MFMA16(vf[db][ks], pb[1][ks], oacc[1][db], 0, 0, 0);
                }
        }

        // epilogue: O[q][d], q = q0+f*16+lr, d = db*16+g4+r
#pragma unroll
        for (int f = 0; f < 2; f++) {
            float inv = 1.0f / l[f];
            int q = q0 + f * 16 + lr;
            unsigned short* op = O + ((size_t)(b * SEQ + q)) * DMODEL + h * HD;
#pragma unroll
            for (int db = 0; db < 8; db++) {
                ushort4 o4;
                o4.x = f2b(oacc[f][db][0] * inv);
                o4.y = f2b(oacc[f][db][1] * inv);
                o4.z = f2b(oacc[f][db][2] * inv);
                o4.w = f2b(oacc[f][db][3] * inv);
                *reinterpret_cast<ushort4*>(op + db * 16 + g4) = o4;
            }
        }
    }
}

extern "C" void kernel_launch(void* const* d_in, const int* in_sizes, int n_in,
                              void* d_out, int out_size, void* d_ws, size_t ws_size,
                              hipStream_t stream) {
    const float* x   = (const float*)d_in[0];
    const float* wqk = (const float*)d_in[1];
    const float* wv  = (const float*)d_in[2];
    const float* wo  = (const float*)d_in[3];

    unsigned short* xb  = (unsigned short*)d_ws;            // [4096][2048]
    unsigned short* wb  = xb  + (size_t)8388608;            // [8192][2048]: wqk | wv | wo
    unsigned short* qkv = wb  + (size_t)16777216;           // [4096][6144]
    unsigned short* qb  = qkv + (size_t)25165824;           // [B][H][S][HD]
    unsigned short* kb  = qb  + (size_t)8388608;
    unsigned short* vt  = kb  + (size_t)8388608;            // [B][H][HD][S]
    unsigned short* ao  = vt  + (size_t)8388608;            // [4096][2048]

    cast_f2b<<<8192, 256, 0, stream>>>(x,   xb, 8388608);
    cast_f2b<<<8192, 256, 0, stream>>>(wqk, wb, 8388608);
    cast_f2b<<<4096, 256, 0, stream>>>(wv,  wb + 8388608, 4194304);
    cast_f2b<<<4096, 256, 0, stream>>>(wo,  wb + 12582912, 4194304);

    gemm_lds<1><<<dim3(48, 32), 256, 0, stream>>>(xb, wb, (void*)qkv, 4096, 6144, 2048);

    rope_qk<<<16384, 256, 0, stream>>>(qkv, qb, kb);
    v_rearr<<<8192, 256, 0, stream>>>(qkv, vt);

    attn5<<<1024, 64, 0, stream>>>(qb, kb, vt, ao);

    gemm_lds<0><<<dim3(16, 32), 256, 0, stream>>>(ao, wb + 12582912, d_out, 4096, 2048, 2048);
}

// Round 10
// 361.514 us; speedup vs baseline: 1.3725x; 1.3725x over previous
//
#include <hip/hip_runtime.h>
#include <hip/hip_bf16.h>

#define NB 2
#define SEQ 2048
#define DMODEL 2048
#define NH 16
#define HD 128
// SM_SCALE * log2(e): softmax computed in exp2 domain
#define QSCALE (0.08838834764831845f * 1.44269504088896f)
#define THRL2 11.5f

using bf16x8 = __attribute__((ext_vector_type(8))) __bf16;
using f32x4  = __attribute__((ext_vector_type(4))) float;

#define MFMA16 __builtin_amdgcn_mfma_f32_16x16x32_bf16

typedef __attribute__((address_space(1))) const void* gptr_t;
typedef __attribute__((address_space(3))) void* lptr_t;

__device__ inline void gload_lds16(const unsigned short* g, unsigned short* l) {
    __builtin_amdgcn_global_load_lds((gptr_t)g, (lptr_t)l, 16, 0, 0);
}

__device__ inline unsigned short f2b(float f) {
    unsigned u = __builtin_bit_cast(unsigned, f);
    u += 0x7FFF + ((u >> 16) & 1);
    return (unsigned short)(u >> 16);
}
__device__ inline float b2f(unsigned short h) {
    return __builtin_bit_cast(float, (unsigned)h << 16);
}
__device__ inline float fexp2(float x) {
    float r;
    asm("v_exp_f32 %0, %1" : "=v"(r) : "v"(x));
    return r;
}
__device__ inline unsigned cvtpk(float a, float b) {   // low=bf16(a), high=bf16(b)
    unsigned r;
    asm("v_cvt_pk_bf16_f32 %0, %1, %2" : "=v"(r) : "v"(a), "v"(b));
    return r;
}

// ---------------- cast fp32 -> bf16, 4 elems/thread ----------------
__global__ void cast_f2b(const float* __restrict__ src, unsigned short* __restrict__ dst, int n) {
    int i = (blockIdx.x * 256 + threadIdx.x) * 4;
    if (i + 3 < n) {
        float4 v = *reinterpret_cast<const float4*>(src + i);
        ushort4 o;
        o.x = f2b(v.x); o.y = f2b(v.y); o.z = f2b(v.z); o.w = f2b(v.w);
        *reinterpret_cast<ushort4*>(dst + i) = o;
    }
}

// ---------------- GEMM (m97 structure, unchanged) ----------------
template<int OUT_BF16>
__global__ __launch_bounds__(256) void gemm_lds(const unsigned short* __restrict__ A,
                                                const unsigned short* __restrict__ Bw,
                                                void* __restrict__ Cout,
                                                int M, int N, int K) {
    __shared__ __align__(16) unsigned short As[128 * 32];
    __shared__ __align__(16) unsigned short Bs[128 * 32];
    int tid = threadIdx.x;
    int lane = tid & 63;
    int w = tid >> 6;
    int row0 = blockIdx.y * 128;
    int col0 = blockIdx.x * 128;

    const unsigned short *pA[2], *pB[2];
    unsigned short *lA[2], *lB[2];
#pragma unroll
    for (int j = 0; j < 2; j++) {
        int c = j * 256 + w * 64 + lane;
        int row = c >> 2;
        int kc = c & 3;
        int ks = kc ^ ((row >> 1) & 3);
        pA[j] = A  + (size_t)(row0 + row) * K + ks * 8;
        pB[j] = Bw + (size_t)(col0 + row) * K + ks * 8;
        int basechunk = j * 256 + w * 64;
        lA[j] = As + basechunk * 8;
        lB[j] = Bs + basechunk * 8;
    }

    int wr = w >> 1, wc = w & 1;
    int lr = lane & 15, g = lane >> 4;
    int offA[4], offB[4];
#pragma unroll
    for (int i = 0; i < 4; i++) {
        int ra = wr * 64 + i * 16 + lr;
        offA[i] = ra * 32 + (g ^ ((ra >> 1) & 3)) * 8;
        int rb = wc * 64 + i * 16 + lr;
        offB[i] = rb * 32 + (g ^ ((rb >> 1) & 3)) * 8;
    }

    f32x4 acc[4][4] = {};

    for (int k = 0; k < K; k += 32) {
#pragma unroll
        for (int j = 0; j < 2; j++) {
            gload_lds16(pA[j] + k, lA[j]);
            gload_lds16(pB[j] + k, lB[j]);
        }
        __syncthreads();

        bf16x8 a[4], b[4];
#pragma unroll
        for (int i = 0; i < 4; i++) a[i] = *reinterpret_cast<const bf16x8*>(As + offA[i]);
#pragma unroll
        for (int j2 = 0; j2 < 4; j2++) b[j2] = *reinterpret_cast<const bf16x8*>(Bs + offB[j2]);
#pragma unroll
        for (int i = 0; i < 4; i++)
#pragma unroll
            for (int j2 = 0; j2 < 4; j2++)
                acc[i][j2] = MFMA16(a[i], b[j2], acc[i][j2], 0, 0, 0);
        __syncthreads();
    }

    int orow = g * 4;
#pragma unroll
    for (int i = 0; i < 4; i++) {
#pragma unroll
        for (int j = 0; j < 4; j++) {
            int r0 = row0 + wr * 64 + i * 16 + orow;
            int c  = col0 + wc * 64 + j * 16 + lr;
#pragma unroll
            for (int r = 0; r < 4; r++) {
                float v = acc[i][j][r];
                if (OUT_BF16)
                    ((unsigned short*)Cout)[(size_t)(r0 + r) * N + c] = f2b(v);
                else
                    ((float*)Cout)[(size_t)(r0 + r) * N + c] = v;
            }
        }
    }
}

// ---------------- RoPE + rearrange Q,K (Q pre-scaled by SM_SCALE*log2e) ----------------
__global__ void rope_qk(const unsigned short* __restrict__ qkv,
                        unsigned short* __restrict__ qb,
                        unsigned short* __restrict__ kb) {
    int idx = blockIdx.x * 256 + threadIdx.x;
    int i = idx & 63;
    int h = (idx >> 6) & 15;
    int t = idx >> 10;
    int s = t & (SEQ - 1);
    int b = t >> 11;

    float inv = exp2f(-13.287712379549449f * (float)i * (1.0f / 64.0f));
    float ang = (float)s * inv;
    float sn, cs;
    sincosf(ang, &sn, &cs);

    const unsigned short* base = qkv + (size_t)t * 6144 + h * 128 + 2 * i;
    unsigned qv = *reinterpret_cast<const unsigned*>(base);
    unsigned kv = *reinterpret_cast<const unsigned*>(base + 2048);

    float qe = b2f((unsigned short)(qv & 0xFFFF));
    float qo = b2f((unsigned short)(qv >> 16));
    float ke = b2f((unsigned short)(kv & 0xFFFF));
    float ko = b2f((unsigned short)(kv >> 16));

    float qe2 = (qe * cs - qo * sn) * QSCALE;
    float qo2 = (qe * sn + qo * cs) * QSCALE;
    float ke2 = ke * cs - ko * sn;
    float ko2 = ke * sn + ko * cs;

    size_t o = ((size_t)(b * NH + h) * SEQ + s) * HD + 2 * i;
    *reinterpret_cast<unsigned*>(qb + o) = (unsigned)f2b(qe2) | ((unsigned)f2b(qo2) << 16);
    *reinterpret_cast<unsigned*>(kb + o) = (unsigned)f2b(ke2) | ((unsigned)f2b(ko2) << 16);
}

// ---------------- V rearrange: qkv -> vt [B][H][HD][S] ----------------
__global__ void v_rearr(const unsigned short* __restrict__ qkv, unsigned short* __restrict__ vt) {
    int idx = blockIdx.x * 256 + threadIdx.x;
    int s4 = (idx & 511) * 4;
    int d  = (idx >> 9) & 127;
    int h  = (idx >> 16) & 15;
    int b  = idx >> 20;
    ushort4 o;
    size_t rbase = (size_t)(b * SEQ + s4) * 6144 + 4096 + h * 128 + d;
    o.x = qkv[rbase];
    o.y = qkv[rbase + 6144];
    o.z = qkv[rbase + 2 * 6144];
    o.w = qkv[rbase + 3 * 6144];
    *reinterpret_cast<ushort4*>(vt + ((size_t)(b * NH + h) * HD + d) * SEQ + s4) = o;
}

// ---------------- flash attention v6 ----------------
// 1 wave/block. Block (p,bh) does 32-row q-tiles p and 63-p -> uniform 33 trips.
// K staged via global_load_lds (no staging VGPRs), double-buffered (2x16KB),
// pre-swizzled global source so linear LDS dest lands in XOR-swizzled layout.
// P 4KB. 36KB LDS -> 4 blocks/CU, all 1024 blocks resident, zero tail.
__global__ __launch_bounds__(64, 1) void attn6(const unsigned short* __restrict__ Q,
                                               const unsigned short* __restrict__ Kb,
                                               const unsigned short* __restrict__ Vt,
                                               unsigned short* __restrict__ O) {
    __shared__ __align__(16) char lds[36864];   // 2x16KB K dbuf + 4KB P

    int lane = threadIdx.x;
    int bid = blockIdx.x;
    int p  = bid >> 5;          // 0..31 -> pair (p, 63-p)
    int bh = bid & 31;          // bid%8 == bh%8 -> head->XCD affinity
    int lr = lane & 15;
    int g  = lane >> 4;
    int g4 = g * 4;
    int lk = g * 8;

    const unsigned short* Qp = Q  + (size_t)bh * SEQ * HD;
    const unsigned short* Kp = Kb + (size_t)bh * SEQ * HD;
    const unsigned short* Vp = Vt + (size_t)bh * HD * SEQ;
    char* pl = lds + 32768;
    int b = bh >> 4;
    int h = bh & 15;

    // staging: issue i covers rows r = i*4 + g, stored col lr holds global chunk lr^(r&7)
    int srcoff[16];
#pragma unroll
    for (int i2 = 0; i2 < 16; ++i2) {
        int r = i2 * 4 + g;
        srcoff[i2] = r * HD + ((lr ^ (r & 7)) * 8);
    }

#define STAGEK(bufbase, kvbase)                                                     \
    {                                                                               \
        const unsigned short* kbase = Kp + (size_t)(kvbase) * HD;                   \
        _Pragma("unroll")                                                           \
        for (int i2 = 0; i2 < 16; ++i2)                                             \
            gload_lds16(kbase + srcoff[i2],                                         \
                        (unsigned short*)(lds + (bufbase) + i2 * 1024));            \
    }

    for (int ph = 0; ph < 2; ++ph) {
        int j  = ph ? (63 - p) : p;
        int q0 = j * 32;
        int ktiles = (j >> 1) + 1;

        bf16x8 qf[2][4];
#pragma unroll
        for (int f = 0; f < 2; f++)
#pragma unroll
            for (int kb = 0; kb < 4; kb++)
                qf[f][kb] = *reinterpret_cast<const bf16x8*>(Qp + (size_t)(q0 + f * 16 + lr) * HD + kb * 32 + lk);

        f32x4 oacc[2][8] = {};
        float m[2] = { -1e30f, -1e30f }, l[2] = { 0.0f, 0.0f };
        int qrow[2] = { q0 + lr, q0 + 16 + lr };

        STAGEK(0, 0);                       // prologue: tile 0 -> buf 0

        int cur = 0;
        for (int t = 0; t < ktiles; ++t) {
            int kv0 = t * 64;
            if (t + 1 < ktiles) {
                STAGEK((cur ^ 1) * 16384, kv0 + 64);
                asm volatile("s_waitcnt vmcnt(16)" ::: "memory");   // tile t's 16 loads done
            } else {
                asm volatile("s_waitcnt vmcnt(0)" ::: "memory");
            }
            __builtin_amdgcn_sched_barrier(0);

            char* kb_c = lds + cur * 16384;
            // ---- QK^T swapped: lane owns q = lane&15, 16 in-lane kv scores ----
            f32x4 s[2][4] = {};
#pragma unroll
            for (int kb = 0; kb < 4; kb++) {
#pragma unroll
                for (int jj = 0; jj < 4; jj++) {
                    int row = jj * 16 + lr;
                    int cin = ((kb * 4 + g) ^ (row & 7));
                    bf16x8 kf = *reinterpret_cast<const bf16x8*>(kb_c + row * 256 + cin * 16);
                    s[0][jj] = MFMA16(kf, qf[0][kb], s[0][jj], 0, 0, 0);
                    s[1][jj] = MFMA16(kf, qf[1][kb], s[1][jj], 0, 0, 0);
                }
            }

            // ---- V prefetch (issue early, consumed at PV) ----
            bf16x8 vf[8][2];
#pragma unroll
            for (int db = 0; db < 8; db++)
#pragma unroll
                for (int ks = 0; ks < 2; ks++)
                    vf[db][ks] = *reinterpret_cast<const bf16x8*>(Vp + (size_t)(db * 16 + lr) * SEQ + kv0 + ks * 32 + lk);

            // ---- in-lane online softmax (exp2 domain, defer-max) ----
#pragma unroll
            for (int f = 0; f < 2; f++) {
                int q = qrow[f];
                bool full = (kv0 + 63 <= q0 + f * 16);   // wave-uniform
                float mx = -1e30f;
                if (full) {
#pragma unroll
                    for (int jj = 0; jj < 4; jj++)
#pragma unroll
                        for (int r = 0; r < 4; r++)
                            mx = fmaxf(mx, s[f][jj][r]);
                } else {
#pragma unroll
                    for (int jj = 0; jj < 4; jj++)
#pragma unroll
                        for (int r = 0; r < 4; r++) {
                            int kv = kv0 + jj * 16 + g4 + r;
                            float v = (kv <= q) ? s[f][jj][r] : -1e30f;
                            s[f][jj][r] = v;
                            mx = fmaxf(mx, v);
                        }
                }
                mx = fmaxf(mx, __shfl_xor(mx, 16));
                mx = fmaxf(mx, __shfl_xor(mx, 32));

                if (!__all(mx <= m[f] + THRL2)) {
                    float mn = fmaxf(m[f], mx);
                    float sc = fexp2(m[f] - mn);
                    m[f] = mn;
                    l[f] *= sc;
#pragma unroll
                    for (int db = 0; db < 8; db++)
#pragma unroll
                        for (int r = 0; r < 4; r++)
                            oacc[f][db][r] *= sc;
                }

                int row = f * 16 + lr;
                int rb = row * 128;
                int sw = (row & 7) << 4;
                float rs = 0.0f;
#pragma unroll
                for (int jj = 0; jj < 4; jj++)
#pragma unroll
                    for (int hh = 0; hh < 2; hh++) {
                        float p0 = fexp2(s[f][jj][2 * hh]     - m[f]);
                        float p1 = fexp2(s[f][jj][2 * hh + 1] - m[f]);
                        rs += p0 + p1;
                        unsigned pk = cvtpk(p0, p1);
                        int colb = jj * 32 + g * 8 + 4 * hh;
                        *reinterpret_cast<unsigned*>(pl + rb + (colb ^ sw)) = pk;
                    }
                rs += __shfl_xor(rs, 16);
                rs += __shfl_xor(rs, 32);
                l[f] += rs;
            }

            asm volatile("s_waitcnt lgkmcnt(0)" ::: "memory");
            __builtin_amdgcn_sched_barrier(0);

            // ---- P fragments + swapped PV ----
            bf16x8 pb[2][2];
#pragma unroll
            for (int f = 0; f < 2; f++)
#pragma unroll
                for (int ks = 0; ks < 2; ks++) {
                    int row = f * 16 + lr;
                    int off = row * 128 + ((ks * 64 + g * 16) ^ ((row & 7) << 4));
                    pb[f][ks] = *reinterpret_cast<const bf16x8*>(pl + off);
                }
#pragma unroll
            for (int db = 0; db < 8; db++)
#pragma unroll
                for (int ks = 0; ks < 2; ks++) {
                    oacc[0][db] = MFMA16(vf[db][ks], pb[0][ks], oacc[0][db], 0, 0, 0);
                    oacc[1][db] = MFMA16(vf[db][ks], pb[1][ks], oacc[1][db], 0, 0, 0);
                }

            cur ^= 1;
        }

        // epilogue: O[q][d], q = q0+f*16+lr, d = db*16+g4+r
#pragma unroll
        for (int f = 0; f < 2; f++) {
            float inv = 1.0f / l[f];
            int q = q0 + f * 16 + lr;
            unsigned short* op = O + ((size_t)(b * SEQ + q)) * DMODEL + h * HD;
#pragma unroll
            for (int db = 0; db < 8; db++) {
                ushort4 o4;
                o4.x = f2b(oacc[f][db][0] * inv);
                o4.y = f2b(oacc[f][db][1] * inv);
                o4.z = f2b(oacc[f][db][2] * inv);
                o4.w = f2b(oacc[f][db][3] * inv);
                *reinterpret_cast<ushort4*>(op + db * 16 + g4) = o4;
            }
        }
    }
#undef STAGEK
}

extern "C" void kernel_launch(void* const* d_in, const int* in_sizes, int n_in,
                              void* d_out, int out_size, void* d_ws, size_t ws_size,
                              hipStream_t stream) {
    const float* x   = (const float*)d_in[0];
    const float* wqk = (const float*)d_in[1];
    const float* wv  = (const float*)d_in[2];
    const float* wo  = (const float*)d_in[3];

    unsigned short* xb  = (unsigned short*)d_ws;            // [4096][2048]
    unsigned short* wb  = xb  + (size_t)8388608;            // [8192][2048]: wqk | wv | wo
    unsigned short* qkv = wb  + (size_t)16777216;           // [4096][6144]
    unsigned short* qb  = qkv + (size_t)25165824;           // [B][H][S][HD]
    unsigned short* kb  = qb  + (size_t)8388608;
    unsigned short* vt  = kb  + (size_t)8388608;            // [B][H][HD][S]
    unsigned short* ao  = vt  + (size_t)8388608;            // [4096][2048]

    cast_f2b<<<8192, 256, 0, stream>>>(x,   xb, 8388608);
    cast_f2b<<<8192, 256, 0, stream>>>(wqk, wb, 8388608);
    cast_f2b<<<4096, 256, 0, stream>>>(wv,  wb + 8388608, 4194304);
    cast_f2b<<<4096, 256, 0, stream>>>(wo,  wb + 12582912, 4194304);

    gemm_lds<1><<<dim3(48, 32), 256, 0, stream>>>(xb, wb, (void*)qkv, 4096, 6144, 2048);

    rope_qk<<<16384, 256, 0, stream>>>(qkv, qb, kb);
    v_rearr<<<8192, 256, 0, stream>>>(qkv, vt);

    attn6<<<1024, 64, 0, stream>>>(qb, kb, vt, ao);

    gemm_lds<0><<<dim3(16, 32), 256, 0, stream>>>(ao, wb + 12582912, d_out, 4096, 2048, 2048);
}

// Round 12
// 329.082 us; speedup vs baseline: 1.5078x; 1.0986x over previous
//
#include <hip/hip_runtime.h>
#include <hip/hip_bf16.h>

#define NB 2
#define SEQ 2048
#define DMODEL 2048
#define NH 16
#define HD 128
// SM_SCALE * log2(e): softmax computed in exp2 domain
#define QSCALE (0.08838834764831845f * 1.44269504088896f)
#define THRL2 11.5f

using bf16x8 = __attribute__((ext_vector_type(8))) __bf16;
using f32x4  = __attribute__((ext_vector_type(4))) float;

#define MFMA16 __builtin_amdgcn_mfma_f32_16x16x32_bf16

typedef __attribute__((address_space(1))) const void* gptr_t;
typedef __attribute__((address_space(3))) void* lptr_t;

__device__ inline void gload_lds16(const unsigned short* g, unsigned short* l) {
    __builtin_amdgcn_global_load_lds((gptr_t)g, (lptr_t)l, 16, 0, 0);
}

__device__ inline unsigned short f2b(float f) {
    unsigned u = __builtin_bit_cast(unsigned, f);
    u += 0x7FFF + ((u >> 16) & 1);
    return (unsigned short)(u >> 16);
}
__device__ inline float b2f(unsigned short h) {
    return __builtin_bit_cast(float, (unsigned)h << 16);
}
__device__ inline float fexp2(float x) {
    float r;
    asm("v_exp_f32 %0, %1" : "=v"(r) : "v"(x));
    return r;
}
__device__ inline unsigned cvtpk(float a, float b) {   // low=bf16(a), high=bf16(b)
    unsigned r;
    asm("v_cvt_pk_bf16_f32 %0, %1, %2" : "=v"(r) : "v"(a), "v"(b));
    return r;
}

// ---------------- cast fp32 -> bf16, 4 elems/thread ----------------
__global__ void cast_f2b(const float* __restrict__ src, unsigned short* __restrict__ dst, int n) {
    int i = (blockIdx.x * 256 + threadIdx.x) * 4;
    if (i + 3 < n) {
        float4 v = *reinterpret_cast<const float4*>(src + i);
        ushort4 o;
        o.x = f2b(v.x); o.y = f2b(v.y); o.z = f2b(v.z); o.w = f2b(v.w);
        *reinterpret_cast<ushort4*>(dst + i) = o;
    }
}

// ---------------- GEMM 8-phase-style: BM=128 BN=256 BK=64, 8 waves ----------------
// Fixed round-11 race: tile-ready s_barrier now sits BETWEEN the vmcnt wait and the
// phase-0 ds_reads (stage is cooperative across waves; per-wave vmcnt alone is not
// visibility). Counted vmcnt(6) in-loop; WAR barrier after phase-1 reads drain.
template<int OUT_BF16>
__global__ __launch_bounds__(512) void gemm8p(const unsigned short* __restrict__ A,
                                              const unsigned short* __restrict__ Bw,
                                              void* __restrict__ Cout,
                                              int M, int N, int K) {
    __shared__ __align__(16) char lds[98304];   // [A0 16K][B0 32K][A1 16K][B1 32K]
    int tid = threadIdx.x;
    int lane = tid & 63;
    int wid = tid >> 6;
    int wm = wid >> 2, wn = wid & 3;
    int row0 = blockIdx.y * 128;
    int col0 = blockIdx.x * 256;
    int lr = lane & 15, g = lane >> 4;

    // staging sources: chunk = i*512 + tid -> (row = chunk>>3, c = chunk&7);
    // LDS slot (row,c) holds global chunk c ^ (((row>>2)&1)<<1)  [inverse of read swizzle]
    const unsigned short* srcA[2];
    const unsigned short* srcB[4];
#pragma unroll
    for (int i = 0; i < 2; i++) {
        int chunk = i * 512 + tid;
        int row = chunk >> 3, c = chunk & 7;
        int cs = c ^ (((row >> 2) & 1) << 1);
        srcA[i] = A + (size_t)(row0 + row) * K + cs * 8;
    }
#pragma unroll
    for (int i = 0; i < 4; i++) {
        int chunk = i * 512 + tid;
        int row = chunk >> 3, c = chunk & 7;
        int cs = c ^ (((row >> 2) & 1) << 1);
        srcB[i] = Bw + (size_t)(col0 + row) * K + cs * 8;
    }

    // fragment LDS byte offsets (read-side swizzle: byte ^= ((row>>2)&1)<<5)
    int offA[4][2], offB[4][2];
#pragma unroll
    for (int i = 0; i < 4; i++) {
        int row = wm * 64 + i * 16 + lr;
#pragma unroll
        for (int ks = 0; ks < 2; ks++)
            offA[i][ks] = row * 128 + ((ks * 64 + g * 16) ^ (((row >> 2) & 1) << 5));
    }
#pragma unroll
    for (int j = 0; j < 4; j++) {
        int row = wn * 64 + j * 16 + lr;
#pragma unroll
        for (int ks = 0; ks < 2; ks++)
            offB[j][ks] = row * 128 + ((ks * 64 + g * 16) ^ (((row >> 2) & 1) << 5));
    }

    f32x4 acc[4][4] = {};
    int NT = K >> 6;

#define STAGE8(t) {                                                                   \
        int kb_ = (t) * 64;                                                           \
        int bs_ = ((t) & 1) * 49152;                                                  \
        _Pragma("unroll")                                                             \
        for (int i_ = 0; i_ < 2; i_++)                                                \
            gload_lds16(srcA[i_] + kb_,                                               \
                (unsigned short*)(lds + bs_ + (i_ * 512 + (tid & ~63)) * 16));        \
        _Pragma("unroll")                                                             \
        for (int i_ = 0; i_ < 4; i_++)                                                \
            gload_lds16(srcB[i_] + kb_,                                               \
                (unsigned short*)(lds + bs_ + 16384 + (i_ * 512 + (tid & ~63)) * 16)); \
    }

    STAGE8(0);                                   // prologue
    for (int t = 0; t < NT; ++t) {
        if (t + 1 < NT) {
            STAGE8(t + 1);                       // into buf[(t+1)&1] (safe: WAR barrier at end of t-1)
            asm volatile("s_waitcnt vmcnt(6)" ::: "memory");   // our 6 tile-t loads landed; 6 in flight
        } else {
            asm volatile("s_waitcnt vmcnt(0)" ::: "memory");
        }
        __builtin_amdgcn_s_barrier();            // ALL waves' tile-t loads landed -> tile ready
        __builtin_amdgcn_sched_barrier(0);

        const char* ab = lds + (t & 1) * 49152;
        const char* bb = ab + 16384;

        // phase 0: all B-frags + A rows {0,1}
        bf16x8 b[4][2], a[2][2];
#pragma unroll
        for (int j = 0; j < 4; j++)
#pragma unroll
            for (int ks = 0; ks < 2; ks++)
                b[j][ks] = *reinterpret_cast<const bf16x8*>(bb + offB[j][ks]);
#pragma unroll
        for (int i = 0; i < 2; i++)
#pragma unroll
            for (int ks = 0; ks < 2; ks++)
                a[i][ks] = *reinterpret_cast<const bf16x8*>(ab + offA[i][ks]);
        asm volatile("s_waitcnt lgkmcnt(0)" ::: "memory");
        __builtin_amdgcn_sched_barrier(0);
        __builtin_amdgcn_s_setprio(1);
#pragma unroll
        for (int ks = 0; ks < 2; ks++)
#pragma unroll
            for (int i = 0; i < 2; i++)
#pragma unroll
                for (int j = 0; j < 4; j++)
                    acc[i][j] = MFMA16(a[i][ks], b[j][ks], acc[i][j], 0, 0, 0);
        __builtin_amdgcn_s_setprio(0);

        // phase 1: A rows {2,3}
        bf16x8 a2[2][2];
#pragma unroll
        for (int i = 0; i < 2; i++)
#pragma unroll
            for (int ks = 0; ks < 2; ks++)
                a2[i][ks] = *reinterpret_cast<const bf16x8*>(ab + offA[2 + i][ks]);
        asm volatile("s_waitcnt lgkmcnt(0)" ::: "memory");
        __builtin_amdgcn_sched_barrier(0);
        __builtin_amdgcn_s_barrier();            // end-of-tile WAR fence: all reads of buf[t&1] retired
        __builtin_amdgcn_sched_barrier(0);
        __builtin_amdgcn_s_setprio(1);
#pragma unroll
        for (int ks = 0; ks < 2; ks++)
#pragma unroll
            for (int i = 0; i < 2; i++)
#pragma unroll
                for (int j = 0; j < 4; j++)
                    acc[2 + i][j] = MFMA16(a2[i][ks], b[j][ks], acc[2 + i][j], 0, 0, 0);
        __builtin_amdgcn_s_setprio(0);
    }
#undef STAGE8

    int orow = g * 4;
#pragma unroll
    for (int i = 0; i < 4; i++) {
#pragma unroll
        for (int j = 0; j < 4; j++) {
            int r0 = row0 + wm * 64 + i * 16 + orow;
            int c  = col0 + wn * 64 + j * 16 + lr;
#pragma unroll
            for (int r = 0; r < 4; r++) {
                float v = acc[i][j][r];
                if (OUT_BF16)
                    ((unsigned short*)Cout)[(size_t)(r0 + r) * N + c] = f2b(v);
                else
                    ((float*)Cout)[(size_t)(r0 + r) * N + c] = v;
            }
        }
    }
}

// ---------------- RoPE + rearrange Q,K (Q pre-scaled by SM_SCALE*log2e) ----------------
__global__ void rope_qk(const unsigned short* __restrict__ qkv,
                        unsigned short* __restrict__ qb,
                        unsigned short* __restrict__ kb) {
    int idx = blockIdx.x * 256 + threadIdx.x;
    int i = idx & 63;
    int h = (idx >> 6) & 15;
    int t = idx >> 10;
    int s = t & (SEQ - 1);
    int b = t >> 11;

    float inv = exp2f(-13.287712379549449f * (float)i * (1.0f / 64.0f));
    float ang = (float)s * inv;
    float sn, cs;
    sincosf(ang, &sn, &cs);

    const unsigned short* base = qkv + (size_t)t * 6144 + h * 128 + 2 * i;
    unsigned qv = *reinterpret_cast<const unsigned*>(base);
    unsigned kv = *reinterpret_cast<const unsigned*>(base + 2048);

    float qe = b2f((unsigned short)(qv & 0xFFFF));
    float qo = b2f((unsigned short)(qv >> 16));
    float ke = b2f((unsigned short)(kv & 0xFFFF));
    float ko = b2f((unsigned short)(kv >> 16));

    float qe2 = (qe * cs - qo * sn) * QSCALE;
    float qo2 = (qe * sn + qo * cs) * QSCALE;
    float ke2 = ke * cs - ko * sn;
    float ko2 = ke * sn + ko * cs;

    size_t o = ((size_t)(b * NH + h) * SEQ + s) * HD + 2 * i;
    *reinterpret_cast<unsigned*>(qb + o) = (unsigned)f2b(qe2) | ((unsigned)f2b(qo2) << 16);
    *reinterpret_cast<unsigned*>(kb + o) = (unsigned)f2b(ke2) | ((unsigned)f2b(ko2) << 16);
}

// ---------------- V rearrange: qkv -> vt [B][H][HD][S] ----------------
__global__ void v_rearr(const unsigned short* __restrict__ qkv, unsigned short* __restrict__ vt) {
    int idx = blockIdx.x * 256 + threadIdx.x;
    int s4 = (idx & 511) * 4;
    int d  = (idx >> 9) & 127;
    int h  = (idx >> 16) & 15;
    int b  = idx >> 20;
    ushort4 o;
    size_t rbase = (size_t)(b * SEQ + s4) * 6144 + 4096 + h * 128 + d;
    o.x = qkv[rbase];
    o.y = qkv[rbase + 6144];
    o.z = qkv[rbase + 2 * 6144];
    o.w = qkv[rbase + 3 * 6144];
    *reinterpret_cast<ushort4*>(vt + ((size_t)(b * NH + h) * HD + d) * SEQ + s4) = o;
}

// ---------------- flash attention v6 (unchanged) ----------------
__global__ __launch_bounds__(64, 1) void attn6(const unsigned short* __restrict__ Q,
                                               const unsigned short* __restrict__ Kb,
                                               const unsigned short* __restrict__ Vt,
                                               unsigned short* __restrict__ O) {
    __shared__ __align__(16) char lds[36864];   // 2x16KB K dbuf + 4KB P

    int lane = threadIdx.x;
    int bid = blockIdx.x;
    int p  = bid >> 5;
    int bh = bid & 31;
    int lr = lane & 15;
    int g  = lane >> 4;
    int g4 = g * 4;
    int lk = g * 8;

    const unsigned short* Qp = Q  + (size_t)bh * SEQ * HD;
    const unsigned short* Kp = Kb + (size_t)bh * SEQ * HD;
    const unsigned short* Vp = Vt + (size_t)bh * HD * SEQ;
    char* pl = lds + 32768;
    int b = bh >> 4;
    int h = bh & 15;

    int srcoff[16];
#pragma unroll
    for (int i2 = 0; i2 < 16; ++i2) {
        int r = i2 * 4 + g;
        srcoff[i2] = r * HD + ((lr ^ (r & 7)) * 8);
    }

#define STAGEK(bufbase, kvbase)                                                     \
    {                                                                               \
        const unsigned short* kbase = Kp + (size_t)(kvbase) * HD;                   \
        _Pragma("unroll")                                                           \
        for (int i2 = 0; i2 < 16; ++i2)                                             \
            gload_lds16(kbase + srcoff[i2],                                         \
                        (unsigned short*)(lds + (bufbase) + i2 * 1024));            \
    }

    for (int ph = 0; ph < 2; ++ph) {
        int j  = ph ? (63 - p) : p;
        int q0 = j * 32;
        int ktiles = (j >> 1) + 1;

        bf16x8 qf[2][4];
#pragma unroll
        for (int f = 0; f < 2; f++)
#pragma unroll
            for (int kb = 0; kb < 4; kb++)
                qf[f][kb] = *reinterpret_cast<const bf16x8*>(Qp + (size_t)(q0 + f * 16 + lr) * HD + kb * 32 + lk);

        f32x4 oacc[2][8] = {};
        float m[2] = { -1e30f, -1e30f }, l[2] = { 0.0f, 0.0f };
        int qrow[2] = { q0 + lr, q0 + 16 + lr };

        STAGEK(0, 0);

        int cur = 0;
        for (int t = 0; t < ktiles; ++t) {
            int kv0 = t * 64;
            if (t + 1 < ktiles) {
                STAGEK((cur ^ 1) * 16384, kv0 + 64);
                asm volatile("s_waitcnt vmcnt(16)" ::: "memory");
            } else {
                asm volatile("s_waitcnt vmcnt(0)" ::: "memory");
            }
            __builtin_amdgcn_sched_barrier(0);

            char* kb_c = lds + cur * 16384;
            f32x4 s[2][4] = {};
#pragma unroll
            for (int kb = 0; kb < 4; kb++) {
#pragma unroll
                for (int jj = 0; jj < 4; jj++) {
                    int row = jj * 16 + lr;
                    int cin = ((kb * 4 + g) ^ (row & 7));
                    bf16x8 kf = *reinterpret_cast<const bf16x8*>(kb_c + row * 256 + cin * 16);
                    s[0][jj] = MFMA16(kf, qf[0][kb], s[0][jj], 0, 0, 0);
                    s[1][jj] = MFMA16(kf, qf[1][kb], s[1][jj], 0, 0, 0);
                }
            }

            bf16x8 vf[8][2];
#pragma unroll
            for (int db = 0; db < 8; db++)
#pragma unroll
                for (int ks = 0; ks < 2; ks++)
                    vf[db][ks] = *reinterpret_cast<const bf16x8*>(Vp + (size_t)(db * 16 + lr) * SEQ + kv0 + ks * 32 + lk);

#pragma unroll
            for (int f = 0; f < 2; f++) {
                int q = qrow[f];
                bool full = (kv0 + 63 <= q0 + f * 16);
                float mx = -1e30f;
                if (full) {
#pragma unroll
                    for (int jj = 0; jj < 4; jj++)
#pragma unroll
                        for (int r = 0; r < 4; r++)
                            mx = fmaxf(mx, s[f][jj][r]);
                } else {
#pragma unroll
                    for (int jj = 0; jj < 4; jj++)
#pragma unroll
                        for (int r = 0; r < 4; r++) {
                            int kv = kv0 + jj * 16 + g4 + r;
                            float v = (kv <= q) ? s[f][jj][r] : -1e30f;
                            s[f][jj][r] = v;
                            mx = fmaxf(mx, v);
                        }
                }
                mx = fmaxf(mx, __shfl_xor(mx, 16));
                mx = fmaxf(mx, __shfl_xor(mx, 32));

                if (!__all(mx <= m[f] + THRL2)) {
                    float mn = fmaxf(m[f], mx);
                    float sc = fexp2(m[f] - mn);
                    m[f] = mn;
                    l[f] *= sc;
#pragma unroll
                    for (int db = 0; db < 8; db++)
#pragma unroll
                        for (int r = 0; r < 4; r++)
                            oacc[f][db][r] *= sc;
                }

                int row = f * 16 + lr;
                int rb = row * 128;
                int sw = (row & 7) << 4;
                float rs = 0.0f;
#pragma unroll
                for (int jj = 0; jj < 4; jj++)
#pragma unroll
                    for (int hh = 0; hh < 2; hh++) {
                        float p0 = fexp2(s[f][jj][2 * hh]     - m[f]);
                        float p1 = fexp2(s[f][jj][2 * hh + 1] - m[f]);
                        rs += p0 + p1;
                        unsigned pk = cvtpk(p0, p1);
                        int colb = jj * 32 + g * 8 + 4 * hh;
                        *reinterpret_cast<unsigned*>(pl + rb + (colb ^ sw)) = pk;
                    }
                rs += __shfl_xor(rs, 16);
                rs += __shfl_xor(rs, 32);
                l[f] += rs;
            }

            asm volatile("s_waitcnt lgkmcnt(0)" ::: "memory");
            __builtin_amdgcn_sched_barrier(0);

            bf16x8 pb[2][2];
#pragma unroll
            for (int f = 0; f < 2; f++)
#pragma unroll
                for (int ks = 0; ks < 2; ks++) {
                    int row = f * 16 + lr;
                    int off = row * 128 + ((ks * 64 + g * 16) ^ ((row & 7) << 4));
                    pb[f][ks] = *reinterpret_cast<const bf16x8*>(pl + off);
                }
#pragma unroll
            for (int db = 0; db < 8; db++)
#pragma unroll
                for (int ks = 0; ks < 2; ks++) {
                    oacc[0][db] = MFMA16(vf[db][ks], pb[0][ks], oacc[0][db], 0, 0, 0);
                    oacc[1][db] = MFMA16(vf[db][ks], pb[1][ks], oacc[1][db], 0, 0, 0);
                }

            cur ^= 1;
        }

#pragma unroll
        for (int f = 0; f < 2; f++) {
            float inv = 1.0f / l[f];
            int q = q0 + f * 16 + lr;
            unsigned short* op = O + ((size_t)(b * SEQ + q)) * DMODEL + h * HD;
#pragma unroll
            for (int db = 0; db < 8; db++) {
                ushort4 o4;
                o4.x = f2b(oacc[f][db][0] * inv);
                o4.y = f2b(oacc[f][db][1] * inv);
                o4.z = f2b(oacc[f][db][2] * inv);
                o4.w = f2b(oacc[f][db][3] * inv);
                *reinterpret_cast<ushort4*>(op + db * 16 + g4) = o4;
            }
        }
    }
#undef STAGEK
}

extern "C" void kernel_launch(void* const* d_in, const int* in_sizes, int n_in,
                              void* d_out, int out_size, void* d_ws, size_t ws_size,
                              hipStream_t stream) {
    const float* x   = (const float*)d_in[0];
    const float* wqk = (const float*)d_in[1];
    const float* wv  = (const float*)d_in[2];
    const float* wo  = (const float*)d_in[3];

    unsigned short* xb  = (unsigned short*)d_ws;            // [4096][2048]
    unsigned short* wb  = xb  + (size_t)8388608;            // [8192][2048]: wqk | wv | wo
    unsigned short* qkv = wb  + (size_t)16777216;           // [4096][6144]
    unsigned short* qb  = qkv + (size_t)25165824;           // [B][H][S][HD]
    unsigned short* kb  = qb  + (size_t)8388608;
    unsigned short* vt  = kb  + (size_t)8388608;            // [B][H][HD][S]
    unsigned short* ao  = vt  + (size_t)8388608;            // [4096][2048]

    cast_f2b<<<8192, 256, 0, stream>>>(x,   xb, 8388608);
    cast_f2b<<<8192, 256, 0, stream>>>(wqk, wb, 8388608);
    cast_f2b<<<4096, 256, 0, stream>>>(wv,  wb + 8388608, 4194304);
    cast_f2b<<<4096, 256, 0, stream>>>(wo,  wb + 12582912, 4194304);

    // QKV projection: 768 blocks (3 exact CU rounds)
    gemm8p<1><<<dim3(24, 32), 512, 0, stream>>>(xb, wb, (void*)qkv, 4096, 6144, 2048);

    rope_qk<<<16384, 256, 0, stream>>>(qkv, qb, kb);
    v_rearr<<<8192, 256, 0, stream>>>(qkv, vt);

    attn6<<<1024, 64, 0, stream>>>(qb, kb, vt, ao);

    // out projection: 256 blocks (1 exact CU round)
    gemm8p<0><<<dim3(8, 32), 512, 0, stream>>>(ao, wb + 12582912, d_out, 4096, 2048, 2048);
}

// Round 13
// 316.576 us; speedup vs baseline: 1.5673x; 1.0395x over previous
//
#include <hip/hip_runtime.h>
#include <hip/hip_bf16.h>

#define NB 2
#define SEQ 2048
#define DMODEL 2048
#define NH 16
#define HD 128
// SM_SCALE * log2(e): softmax computed in exp2 domain
#define QSCALE (0.08838834764831845f * 1.44269504088896f)
#define THRL2 11.5f

using bf16x8 = __attribute__((ext_vector_type(8))) __bf16;
using f32x4  = __attribute__((ext_vector_type(4))) float;

#define MFMA16 __builtin_amdgcn_mfma_f32_16x16x32_bf16

typedef __attribute__((address_space(1))) const void* gptr_t;
typedef __attribute__((address_space(3))) void* lptr_t;

__device__ inline void gload_lds16(const unsigned short* g, unsigned short* l) {
    __builtin_amdgcn_global_load_lds((gptr_t)g, (lptr_t)l, 16, 0, 0);
}

__device__ inline unsigned short f2b(float f) {
    unsigned u = __builtin_bit_cast(unsigned, f);
    u += 0x7FFF + ((u >> 16) & 1);
    return (unsigned short)(u >> 16);
}
__device__ inline float b2f(unsigned short h) {
    return __builtin_bit_cast(float, (unsigned)h << 16);
}
__device__ inline float fexp2(float x) {
    float r;
    asm("v_exp_f32 %0, %1" : "=v"(r) : "v"(x));
    return r;
}
__device__ inline unsigned cvtpk(float a, float b) {   // low=bf16(a), high=bf16(b)
    unsigned r;
    asm("v_cvt_pk_bf16_f32 %0, %1, %2" : "=v"(r) : "v"(a), "v"(b));
    return r;
}

// ---------------- cast fp32 -> bf16, 4 elems/thread ----------------
__global__ void cast_f2b(const float* __restrict__ src, unsigned short* __restrict__ dst, int n) {
    int i = (blockIdx.x * 256 + threadIdx.x) * 4;
    if (i + 3 < n) {
        float4 v = *reinterpret_cast<const float4*>(src + i);
        ushort4 o;
        o.x = f2b(v.x); o.y = f2b(v.y); o.z = f2b(v.z); o.w = f2b(v.w);
        *reinterpret_cast<ushort4*>(dst + i) = o;
    }
}

// ---------------- GEMM: BM=128 BN=256 BK=64, 8 waves, counted-vmcnt schedule ----------------
// LDS per buffer: A = [2 ksub][128 rows][32 shorts], B = [2 ksub][256 rows][32 shorts]
// -- each BK=32 sub-tile uses the m97 zero-conflict layout (slot = g ^ ((row>>1)&3)).
// Schedule (round-12-verified): STAGE(t+1) -> vmcnt(6) -> s_barrier -> phase0 -> phase1
// with WAR s_barrier after phase-1 reads drain. Never vmcnt(0) in-loop.
template<int OUT_BF16>
__global__ __launch_bounds__(512) void gemm8p(const unsigned short* __restrict__ A,
                                              const unsigned short* __restrict__ Bw,
                                              void* __restrict__ Cout,
                                              int M, int N, int K) {
    __shared__ __align__(16) char lds[98304];   // [A0 16K][B0 32K][A1 16K][B1 32K]
    int tid = threadIdx.x;
    int lane = tid & 63;
    int wid = tid >> 6;
    int wm = wid >> 2, wn = wid & 3;
    int row0 = blockIdx.y * 128;
    int col0 = blockIdx.x * 256;
    int lr = lane & 15, g = lane >> 4;

    // staging sources (inverse of read swizzle, per BK=32 sub-tile):
    // A: 1024 chunks/tile; thread covers chunks i*512+tid (i=0,1)
    //    chunk -> ksub = chunk>>9, row = (chunk&511)>>2, c = chunk&3
    //    LDS slot (ksub,row,c) holds global k-chunk c ^ ((row>>1)&3) of k-sub ksub
    const unsigned short* srcA[2];
    const unsigned short* srcB[4];
#pragma unroll
    for (int i = 0; i < 2; i++) {
        int chunk = i * 512 + tid;
        int ksub = chunk >> 9;
        int cw = chunk & 511;
        int row = cw >> 2, c = cw & 3;
        int cs = c ^ ((row >> 1) & 3);
        srcA[i] = A + (size_t)(row0 + row) * K + ksub * 32 + cs * 8;
    }
    // B: 2048 chunks/tile; thread covers chunks i*512+tid (i=0..3)
#pragma unroll
    for (int i = 0; i < 4; i++) {
        int chunk = i * 512 + tid;
        int ksub = chunk >> 10;
        int cw = chunk & 1023;
        int row = cw >> 2, c = cw & 3;
        int cs = c ^ ((row >> 1) & 3);
        srcB[i] = Bw + (size_t)(col0 + row) * K + ksub * 32 + cs * 8;
    }

    // fragment read offsets (m97 zero-conflict pattern per sub-tile)
    int offA[4][2], offB[4][2];
#pragma unroll
    for (int i = 0; i < 4; i++) {
        int row = wm * 64 + i * 16 + lr;
#pragma unroll
        for (int ks = 0; ks < 2; ks++)
            offA[i][ks] = ks * 8192 + row * 64 + ((g ^ ((row >> 1) & 3)) * 16);
    }
#pragma unroll
    for (int j = 0; j < 4; j++) {
        int row = wn * 64 + j * 16 + lr;
#pragma unroll
        for (int ks = 0; ks < 2; ks++)
            offB[j][ks] = ks * 16384 + row * 64 + ((g ^ ((row >> 1) & 3)) * 16);
    }

    f32x4 acc[4][4] = {};
    int NT = K >> 6;

#define STAGE8(t) {                                                                   \
        int kb_ = (t) * 64;                                                           \
        int bs_ = ((t) & 1) * 49152;                                                  \
        _Pragma("unroll")                                                             \
        for (int i_ = 0; i_ < 2; i_++)                                                \
            gload_lds16(srcA[i_] + kb_,                                               \
                (unsigned short*)(lds + bs_ + (i_ * 512 + (tid & ~63)) * 16));        \
        _Pragma("unroll")                                                             \
        for (int i_ = 0; i_ < 4; i_++)                                                \
            gload_lds16(srcB[i_] + kb_,                                               \
                (unsigned short*)(lds + bs_ + 16384 + (i_ * 512 + (tid & ~63)) * 16)); \
    }

    STAGE8(0);                                   // prologue
    for (int t = 0; t < NT; ++t) {
        if (t + 1 < NT) {
            STAGE8(t + 1);                       // into buf[(t+1)&1] (vacated: WAR barrier end of t-1)
            asm volatile("s_waitcnt vmcnt(6)" ::: "memory");   // our tile-t loads landed; 6 in flight
        } else {
            asm volatile("s_waitcnt vmcnt(0)" ::: "memory");
        }
        __builtin_amdgcn_s_barrier();            // ALL waves' tile-t loads landed -> tile ready
        __builtin_amdgcn_sched_barrier(0);

        const char* ab = lds + (t & 1) * 49152;
        const char* bb = ab + 16384;

        // phase 0: all B-frags + A rows {0,1}
        bf16x8 b[4][2], a[2][2];
#pragma unroll
        for (int j = 0; j < 4; j++)
#pragma unroll
            for (int ks = 0; ks < 2; ks++)
                b[j][ks] = *reinterpret_cast<const bf16x8*>(bb + offB[j][ks]);
#pragma unroll
        for (int i = 0; i < 2; i++)
#pragma unroll
            for (int ks = 0; ks < 2; ks++)
                a[i][ks] = *reinterpret_cast<const bf16x8*>(ab + offA[i][ks]);
        asm volatile("s_waitcnt lgkmcnt(0)" ::: "memory");
        __builtin_amdgcn_sched_barrier(0);
        __builtin_amdgcn_s_setprio(1);
#pragma unroll
        for (int ks = 0; ks < 2; ks++)
#pragma unroll
            for (int i = 0; i < 2; i++)
#pragma unroll
                for (int j = 0; j < 4; j++)
                    acc[i][j] = MFMA16(a[i][ks], b[j][ks], acc[i][j], 0, 0, 0);
        __builtin_amdgcn_s_setprio(0);

        // phase 1: A rows {2,3}
        bf16x8 a2[2][2];
#pragma unroll
        for (int i = 0; i < 2; i++)
#pragma unroll
            for (int ks = 0; ks < 2; ks++)
                a2[i][ks] = *reinterpret_cast<const bf16x8*>(ab + offA[2 + i][ks]);
        asm volatile("s_waitcnt lgkmcnt(0)" ::: "memory");
        __builtin_amdgcn_sched_barrier(0);
        __builtin_amdgcn_s_barrier();            // end-of-tile WAR fence: all reads of buf[t&1] retired
        __builtin_amdgcn_sched_barrier(0);
        __builtin_amdgcn_s_setprio(1);
#pragma unroll
        for (int ks = 0; ks < 2; ks++)
#pragma unroll
            for (int i = 0; i < 2; i++)
#pragma unroll
                for (int j = 0; j < 4; j++)
                    acc[2 + i][j] = MFMA16(a2[i][ks], b[j][ks], acc[2 + i][j], 0, 0, 0);
        __builtin_amdgcn_s_setprio(0);
    }
#undef STAGE8

    int orow = g * 4;
#pragma unroll
    for (int i = 0; i < 4; i++) {
#pragma unroll
        for (int j = 0; j < 4; j++) {
            int r0 = row0 + wm * 64 + i * 16 + orow;
            int c  = col0 + wn * 64 + j * 16 + lr;
#pragma unroll
            for (int r = 0; r < 4; r++) {
                float v = acc[i][j][r];
                if (OUT_BF16)
                    ((unsigned short*)Cout)[(size_t)(r0 + r) * N + c] = f2b(v);
                else
                    ((float*)Cout)[(size_t)(r0 + r) * N + c] = v;
            }
        }
    }
}

// ---------------- RoPE + rearrange Q,K (Q pre-scaled by SM_SCALE*log2e) ----------------
__global__ void rope_qk(const unsigned short* __restrict__ qkv,
                        unsigned short* __restrict__ qb,
                        unsigned short* __restrict__ kb) {
    int idx = blockIdx.x * 256 + threadIdx.x;
    int i = idx & 63;
    int h = (idx >> 6) & 15;
    int t = idx >> 10;
    int s = t & (SEQ - 1);
    int b = t >> 11;

    float inv = exp2f(-13.287712379549449f * (float)i * (1.0f / 64.0f));
    float ang = (float)s * inv;
    float sn, cs;
    sincosf(ang, &sn, &cs);

    const unsigned short* base = qkv + (size_t)t * 6144 + h * 128 + 2 * i;
    unsigned qv = *reinterpret_cast<const unsigned*>(base);
    unsigned kv = *reinterpret_cast<const unsigned*>(base + 2048);

    float qe = b2f((unsigned short)(qv & 0xFFFF));
    float qo = b2f((unsigned short)(qv >> 16));
    float ke = b2f((unsigned short)(kv & 0xFFFF));
    float ko = b2f((unsigned short)(kv >> 16));

    float qe2 = (qe * cs - qo * sn) * QSCALE;
    float qo2 = (qe * sn + qo * cs) * QSCALE;
    float ke2 = ke * cs - ko * sn;
    float ko2 = ke * sn + ko * cs;

    size_t o = ((size_t)(b * NH + h) * SEQ + s) * HD + 2 * i;
    *reinterpret_cast<unsigned*>(qb + o) = (unsigned)f2b(qe2) | ((unsigned)f2b(qo2) << 16);
    *reinterpret_cast<unsigned*>(kb + o) = (unsigned)f2b(ke2) | ((unsigned)f2b(ko2) << 16);
}

// ---------------- V rearrange: qkv -> vt [B][H][HD][S] ----------------
__global__ void v_rearr(const unsigned short* __restrict__ qkv, unsigned short* __restrict__ vt) {
    int idx = blockIdx.x * 256 + threadIdx.x;
    int s4 = (idx & 511) * 4;
    int d  = (idx >> 9) & 127;
    int h  = (idx >> 16) & 15;
    int b  = idx >> 20;
    ushort4 o;
    size_t rbase = (size_t)(b * SEQ + s4) * 6144 + 4096 + h * 128 + d;
    o.x = qkv[rbase];
    o.y = qkv[rbase + 6144];
    o.z = qkv[rbase + 2 * 6144];
    o.w = qkv[rbase + 3 * 6144];
    *reinterpret_cast<ushort4*>(vt + ((size_t)(b * NH + h) * HD + d) * SEQ + s4) = o;
}

// ---------------- flash attention v6 (unchanged) ----------------
__global__ __launch_bounds__(64, 1) void attn6(const unsigned short* __restrict__ Q,
                                               const unsigned short* __restrict__ Kb,
                                               const unsigned short* __restrict__ Vt,
                                               unsigned short* __restrict__ O) {
    __shared__ __align__(16) char lds[36864];   // 2x16KB K dbuf + 4KB P

    int lane = threadIdx.x;
    int bid = blockIdx.x;
    int p  = bid >> 5;
    int bh = bid & 31;
    int lr = lane & 15;
    int g  = lane >> 4;
    int g4 = g * 4;
    int lk = g * 8;

    const unsigned short* Qp = Q  + (size_t)bh * SEQ * HD;
    const unsigned short* Kp = Kb + (size_t)bh * SEQ * HD;
    const unsigned short* Vp = Vt + (size_t)bh * HD * SEQ;
    char* pl = lds + 32768;
    int b = bh >> 4;
    int h = bh & 15;

    int srcoff[16];
#pragma unroll
    for (int i2 = 0; i2 < 16; ++i2) {
        int r = i2 * 4 + g;
        srcoff[i2] = r * HD + ((lr ^ (r & 7)) * 8);
    }

#define STAGEK(bufbase, kvbase)                                                     \
    {                                                                               \
        const unsigned short* kbase = Kp + (size_t)(kvbase) * HD;                   \
        _Pragma("unroll")                                                           \
        for (int i2 = 0; i2 < 16; ++i2)                                             \
            gload_lds16(kbase + srcoff[i2],                                         \
                        (unsigned short*)(lds + (bufbase) + i2 * 1024));            \
    }

    for (int ph = 0; ph < 2; ++ph) {
        int j  = ph ? (63 - p) : p;
        int q0 = j * 32;
        int ktiles = (j >> 1) + 1;

        bf16x8 qf[2][4];
#pragma unroll
        for (int f = 0; f < 2; f++)
#pragma unroll
            for (int kb = 0; kb < 4; kb++)
                qf[f][kb] = *reinterpret_cast<const bf16x8*>(Qp + (size_t)(q0 + f * 16 + lr) * HD + kb * 32 + lk);

        f32x4 oacc[2][8] = {};
        float m[2] = { -1e30f, -1e30f }, l[2] = { 0.0f, 0.0f };
        int qrow[2] = { q0 + lr, q0 + 16 + lr };

        STAGEK(0, 0);

        int cur = 0;
        for (int t = 0; t < ktiles; ++t) {
            int kv0 = t * 64;
            if (t + 1 < ktiles) {
                STAGEK((cur ^ 1) * 16384, kv0 + 64);
                asm volatile("s_waitcnt vmcnt(16)" ::: "memory");
            } else {
                asm volatile("s_waitcnt vmcnt(0)" ::: "memory");
            }
            __builtin_amdgcn_sched_barrier(0);

            char* kb_c = lds + cur * 16384;
            f32x4 s[2][4] = {};
#pragma unroll
            for (int kb = 0; kb < 4; kb++) {
#pragma unroll
                for (int jj = 0; jj < 4; jj++) {
                    int row = jj * 16 + lr;
                    int cin = ((kb * 4 + g) ^ (row & 7));
                    bf16x8 kf = *reinterpret_cast<const bf16x8*>(kb_c + row * 256 + cin * 16);
                    s[0][jj] = MFMA16(kf, qf[0][kb], s[0][jj], 0, 0, 0);
                    s[1][jj] = MFMA16(kf, qf[1][kb], s[1][jj], 0, 0, 0);
                }
            }

            bf16x8 vf[8][2];
#pragma unroll
            for (int db = 0; db < 8; db++)
#pragma unroll
                for (int ks = 0; ks < 2; ks++)
                    vf[db][ks] = *reinterpret_cast<const bf16x8*>(Vp + (size_t)(db * 16 + lr) * SEQ + kv0 + ks * 32 + lk);

#pragma unroll
            for (int f = 0; f < 2; f++) {
                int q = qrow[f];
                bool full = (kv0 + 63 <= q0 + f * 16);
                float mx = -1e30f;
                if (full) {
#pragma unroll
                    for (int jj = 0; jj < 4; jj++)
#pragma unroll
                        for (int r = 0; r < 4; r++)
                            mx = fmaxf(mx, s[f][jj][r]);
                } else {
#pragma unroll
                    for (int jj = 0; jj < 4; jj++)
#pragma unroll
                        for (int r = 0; r < 4; r++) {
                            int kv = kv0 + jj * 16 + g4 + r;
                            float v = (kv <= q) ? s[f][jj][r] : -1e30f;
                            s[f][jj][r] = v;
                            mx = fmaxf(mx, v);
                        }
                }
                mx = fmaxf(mx, __shfl_xor(mx, 16));
                mx = fmaxf(mx, __shfl_xor(mx, 32));

                if (!__all(mx <= m[f] + THRL2)) {
                    float mn = fmaxf(m[f], mx);
                    float sc = fexp2(m[f] - mn);
                    m[f] = mn;
                    l[f] *= sc;
#pragma unroll
                    for (int db = 0; db < 8; db++)
#pragma unroll
                        for (int r = 0; r < 4; r++)
                            oacc[f][db][r] *= sc;
                }

                int row = f * 16 + lr;
                int rb = row * 128;
                int sw = (row & 7) << 4;
                float rs = 0.0f;
#pragma unroll
                for (int jj = 0; jj < 4; jj++)
#pragma unroll
                    for (int hh = 0; hh < 2; hh++) {
                        float p0 = fexp2(s[f][jj][2 * hh]     - m[f]);
                        float p1 = fexp2(s[f][jj][2 * hh + 1] - m[f]);
                        rs += p0 + p1;
                        unsigned pk = cvtpk(p0, p1);
                        int colb = jj * 32 + g * 8 + 4 * hh;
                        *reinterpret_cast<unsigned*>(pl + rb + (colb ^ sw)) = pk;
                    }
                rs += __shfl_xor(rs, 16);
                rs += __shfl_xor(rs, 32);
                l[f] += rs;
            }

            asm volatile("s_waitcnt lgkmcnt(0)" ::: "memory");
            __builtin_amdgcn_sched_barrier(0);

            bf16x8 pb[2][2];
#pragma unroll
            for (int f = 0; f < 2; f++)
#pragma unroll
                for (int ks = 0; ks < 2; ks++) {
                    int row = f * 16 + lr;
                    int off = row * 128 + ((ks * 64 + g * 16) ^ ((row & 7) << 4));
                    pb[f][ks] = *reinterpret_cast<const bf16x8*>(pl + off);
                }
#pragma unroll
            for (int db = 0; db < 8; db++)
#pragma unroll
                for (int ks = 0; ks < 2; ks++) {
                    oacc[0][db] = MFMA16(vf[db][ks], pb[0][ks], oacc[0][db], 0, 0, 0);
                    oacc[1][db] = MFMA16(vf[db][ks], pb[1][ks], oacc[1][db], 0, 0, 0);
                }

            cur ^= 1;
        }

#pragma unroll
        for (int f = 0; f < 2; f++) {
            float inv = 1.0f / l[f];
            int q = q0 + f * 16 + lr;
            unsigned short* op = O + ((size_t)(b * SEQ + q)) * DMODEL + h * HD;
#pragma unroll
            for (int db = 0; db < 8; db++) {
                ushort4 o4;
                o4.x = f2b(oacc[f][db][0] * inv);
                o4.y = f2b(oacc[f][db][1] * inv);
                o4.z = f2b(oacc[f][db][2] * inv);
                o4.w = f2b(oacc[f][db][3] * inv);
                *reinterpret_cast<ushort4*>(op + db * 16 + g4) = o4;
            }
        }
    }
#undef STAGEK
}

extern "C" void kernel_launch(void* const* d_in, const int* in_sizes, int n_in,
                              void* d_out, int out_size, void* d_ws, size_t ws_size,
                              hipStream_t stream) {
    const float* x   = (const float*)d_in[0];
    const float* wqk = (const float*)d_in[1];
    const float* wv  = (const float*)d_in[2];
    const float* wo  = (const float*)d_in[3];

    unsigned short* xb  = (unsigned short*)d_ws;            // [4096][2048]
    unsigned short* wb  = xb  + (size_t)8388608;            // [8192][2048]: wqk | wv | wo
    unsigned short* qkv = wb  + (size_t)16777216;           // [4096][6144]
    unsigned short* qb  = qkv + (size_t)25165824;           // [B][H][S][HD]
    unsigned short* kb  = qb  + (size_t)8388608;
    unsigned short* vt  = kb  + (size_t)8388608;            // [B][H][HD][S]
    unsigned short* ao  = vt  + (size_t)8388608;            // [4096][2048]

    cast_f2b<<<8192, 256, 0, stream>>>(x,   xb, 8388608);
    cast_f2b<<<8192, 256, 0, stream>>>(wqk, wb, 8388608);
    cast_f2b<<<4096, 256, 0, stream>>>(wv,  wb + 8388608, 4194304);
    cast_f2b<<<4096, 256, 0, stream>>>(wo,  wb + 12582912, 4194304);

    // QKV projection: 768 blocks (3 exact CU rounds)
    gemm8p<1><<<dim3(24, 32), 512, 0, stream>>>(xb, wb, (void*)qkv, 4096, 6144, 2048);

    rope_qk<<<16384, 256, 0, stream>>>(qkv, qb, kb);
    v_rearr<<<8192, 256, 0, stream>>>(qkv, vt);

    attn6<<<1024, 64, 0, stream>>>(qb, kb, vt, ao);

    // out projection: 256 blocks (1 exact CU round)
    gemm8p<0><<<dim3(8, 32), 512, 0, stream>>>(ao, wb + 12582912, d_out, 4096, 2048, 2048);
}